// Round 15
// baseline (48.846 us; speedup 1.0000x reference)
//
#include <hip/hip_runtime.h>
#include <stdint.h>

#define B_N   65536
#define NIC   64
#define NIW   64
#define NH    128
#define NA    5
#define D2    128   // 2*NIC

#define PARTITIONABLE 1

#define NBLK      512
#define P2_NCHUNK 51
#define P2_R      1286  // worst-case slice length

// ws: gcnt[5] ints in [0,4096) ; glist 5*B_N ints at 4096 ; wPrep after.
#define WS_GLIST_OFF   4096
#define WS_PREP_OFF    (WS_GLIST_OFF + NA * B_N * 4)

typedef __attribute__((ext_vector_type(8))) short short8;
typedef __attribute__((ext_vector_type(4))) float f32x4;

__device__ __forceinline__ ushort f2bf(float f) {
  uint32_t u = __float_as_uint(f);
  uint32_t r = (u + 0x7FFFu + ((u >> 16) & 1u)) >> 16;  // RNE
  return (ushort)r;
}

__device__ __forceinline__ void split2(float f, ushort& h, ushort& l) {
  h = f2bf(f);
  l = f2bf(f - __uint_as_float(((uint32_t)h) << 16));
}

__device__ __forceinline__ void threefry2x32_k042(uint32_t x0, uint32_t x1,
                                                  uint32_t& o0, uint32_t& o1) {
  const uint32_t ks0 = 0u;
  const uint32_t ks1 = 42u;
  const uint32_t ks2 = 0x1BD11BDAu ^ 0u ^ 42u;
  x0 += ks0; x1 += ks1;
#define TF_RND(r) { x0 += x1; x1 = (x1 << (r)) | (x1 >> (32 - (r))); x1 ^= x0; }
  TF_RND(13) TF_RND(15) TF_RND(26) TF_RND(6)
  x0 += ks1; x1 += ks2 + 1u;
  TF_RND(17) TF_RND(29) TF_RND(16) TF_RND(24)
  x0 += ks2; x1 += ks0 + 2u;
  TF_RND(13) TF_RND(15) TF_RND(26) TF_RND(6)
  x0 += ks0; x1 += ks1 + 3u;
  TF_RND(17) TF_RND(29) TF_RND(16) TF_RND(24)
  x0 += ks1; x1 += ks2 + 4u;
  TF_RND(13) TF_RND(15) TF_RND(26) TF_RND(6)
  x0 += ks2; x1 += ks0 + 5u;
#undef TF_RND
  o0 = x0; o1 = x1;
}

__device__ __forceinline__ float gumbel_at(uint32_t idx) {
  uint32_t bits;
#if PARTITIONABLE
  uint32_t a, b;
  threefry2x32_k042(0u, idx, a, b);
  bits = a ^ b;
#else
  const uint32_t HALF = (uint32_t)(B_N * NA) / 2u;
  uint32_t a, b;
  if (idx < HALF) { threefry2x32_k042(idx, idx + HALF, a, b); bits = a; }
  else            { threefry2x32_k042(idx - HALF, idx, a, b); bits = b; }
#endif
  const float f = __uint_as_float((bits >> 9) | 0x3f800000u) - 1.0f;
  const double u = (f == 0.0f) ? (double)0x1p-126 : (double)f;
  const float nl = (float)(-log(u));
  const float g  = (float)(-log((double)nl));
  return g;
}

// ---------------- Phase 1: policy MLP + bucketed list build + prepack -------
// A-frag: row = lane&15, k = 32*kt + 8*(lane>>4) + j
// D     : col = ct*16 + (lane&15), row(local16) = (lane>>4)*4 + r
__global__ __launch_bounds__(512, 4) void policy_kernel(
    const int* __restrict__ x, const int* __restrict__ y,
    const float* __restrict__ cemb, const float* __restrict__ wemb,
    const float* __restrict__ Wp1, const float* __restrict__ bp1,
    const float* __restrict__ Wp2, const float* __restrict__ bp2,
    const float* __restrict__ We1, const float* __restrict__ We2,
    float* __restrict__ out_wemb, int* __restrict__ gcnt,
    int* __restrict__ glist, ushort* __restrict__ wPrep) {
  __shared__ __align__(16) ushort sW1h[16384];   // 32 KB Wp1 hi frags
  __shared__ __align__(16) ushort sW1l[16384];   // 32 KB Wp1 lo frags
  __shared__ __align__(16) float sW2t[NA][NH];   // Wp2^T
  __shared__ __align__(16) float sb1[NH];
  __shared__ __align__(16) float sbp2[8];
  __shared__ ushort sBList[NA][128];
  __shared__ int sBCnt[NA];
  __shared__ int sBase[8];

  const int tid = threadIdx.x;

  if (blockIdx.x >= NBLK) {
    // ---- prepack expert a's We1/We2 into bf16 fragment order (r6 verbatim) --
    const int a = blockIdx.x - NBLK;
    ushort* wp = wPrep + (size_t)a * 24576;
    {
      const float* W1g = We1 + (size_t)a * D2 * NH;
      const int n = tid & 127, q = tid >> 7;
      const int fb = (n >> 4) * 4 + q;
      const int cc = n & 15;
#pragma unroll
      for (int grp = 0; grp < 4; grp++) {
        short8 pk;
#pragma unroll
        for (int j = 0; j < 8; j++)
          pk[j] = (short)f2bf(W1g[(32 * q + 8 * grp + j) * NH + n]);
        *(short8*)&wp[fb * 512 + (cc + 16 * grp) * 8] = pk;
      }
    }
    {
      const float* W2g = We2 + (size_t)a * NH * NIW;
      const int o = tid & 63, hq = tid >> 6;
      const int fb = (o >> 4) * 4 + (hq >> 1);
      const int cc = o & 15;
#pragma unroll
      for (int g2 = 0; g2 < 2; g2++) {
        const int grp = (hq & 1) * 2 + g2;
        short8 pk;
#pragma unroll
        for (int j = 0; j < 8; j++)
          pk[j] = (short)f2bf(W2g[(16 * hq + 8 * g2 + j) * NIW + o]);
        *(short8*)&wp[16384 + fb * 512 + (cc + 16 * grp) * 8] = pk;
      }
    }
    return;
  }

  const int base = blockIdx.x * 128;

  {
    const int n = tid & 127, q = tid >> 7;
    const int fb = (n >> 4) * 4 + q;
    const int cc = n & 15;
#pragma unroll
    for (int grp = 0; grp < 4; grp++) {
      short8 ph, pl;
#pragma unroll
      for (int j = 0; j < 8; j++) {
        const int k = 32 * q + 8 * grp + j;
        ushort hh, ll;
        split2(Wp1[k * NH + n], hh, ll);
        ph[j] = (short)hh;
        pl[j] = (short)ll;
      }
      *(short8*)&sW1h[fb * 512 + (cc + 16 * grp) * 8] = ph;
      *(short8*)&sW1l[fb * 512 + (cc + 16 * grp) * 8] = pl;
    }
    if (tid < NH) sb1[tid] = bp1[tid];
    if (tid < NA * 32) {
      const int a = tid >> 5, k0 = (tid & 31) * 4;
#pragma unroll
      for (int j = 0; j < 4; j++) sW2t[a][k0 + j] = Wp2[(k0 + j) * NA + a];
    }
    if (tid < NA) sbp2[tid] = bp2[tid];
    if (tid < NA) sBCnt[tid] = 0;
  }

  const int wave = tid >> 6, lane = tid & 63;
  const int c16 = lane & 15, h2 = lane >> 4;

  const int grow = base + wave * 16 + c16;
  const int2 xi2p = ((const int2*)x)[grow];
  const int xi0 = xi2p.x, xi1 = xi2p.y;
  short8 Ah[4], Al[4];
#pragma unroll
  for (int kt = 0; kt < 4; kt++) {
    const int xi = (kt < 2) ? xi0 : xi1;
    const float* src = cemb + (size_t)xi * NIC + (kt & 1) * 32 + h2 * 8;
    const float4 aa = *(const float4*)src;
    const float4 bb = *(const float4*)(src + 4);
    ushort hh, ll;
    short8 ph, pl;
    split2(aa.x, hh, ll); ph[0] = (short)hh; pl[0] = (short)ll;
    split2(aa.y, hh, ll); ph[1] = (short)hh; pl[1] = (short)ll;
    split2(aa.z, hh, ll); ph[2] = (short)hh; pl[2] = (short)ll;
    split2(aa.w, hh, ll); ph[3] = (short)hh; pl[3] = (short)ll;
    split2(bb.x, hh, ll); ph[4] = (short)hh; pl[4] = (short)ll;
    split2(bb.y, hh, ll); ph[5] = (short)hh; pl[5] = (short)ll;
    split2(bb.z, hh, ll); ph[6] = (short)hh; pl[6] = (short)ll;
    split2(bb.w, hh, ll); ph[7] = (short)hh; pl[7] = (short)ll;
    Ah[kt] = ph;
    Al[kt] = pl;
  }
  __syncthreads();

  float part[4][5];
#pragma unroll
  for (int r = 0; r < 4; r++)
#pragma unroll
    for (int a = 0; a < NA; a++) part[r][a] = 0.0f;

#pragma unroll
  for (int half = 0; half < 2; half++) {
    f32x4 acc[4];
#pragma unroll
    for (int c2 = 0; c2 < 4; c2++) {
      const float bv = sb1[(half * 4 + c2) * 16 + c16];
      acc[c2] = (f32x4){bv, bv, bv, bv};
    }
#pragma unroll
    for (int kt = 0; kt < 4; kt++) {
#pragma unroll
      for (int c2 = 0; c2 < 4; c2++) {
        const int fb = (half * 4 + c2) * 4 + kt;
        const short8 Bh = *(const short8*)&sW1h[fb * 512 + lane * 8];
        const short8 Bl = *(const short8*)&sW1l[fb * 512 + lane * 8];
        acc[c2] = __builtin_amdgcn_mfma_f32_16x16x32_bf16(Ah[kt], Bh, acc[c2], 0, 0, 0);
        acc[c2] = __builtin_amdgcn_mfma_f32_16x16x32_bf16(Al[kt], Bh, acc[c2], 0, 0, 0);
        acc[c2] = __builtin_amdgcn_mfma_f32_16x16x32_bf16(Ah[kt], Bl, acc[c2], 0, 0, 0);
      }
    }
#pragma unroll
    for (int c2 = 0; c2 < 4; c2++) {
      const int ct = half * 4 + c2;
      float w[NA];
#pragma unroll
      for (int a = 0; a < NA; a++) w[a] = sW2t[a][ct * 16 + c16];
#pragma unroll
      for (int r = 0; r < 4; r++) {
        const float hv = fmaxf(acc[c2][r], 0.0f);
#pragma unroll
        for (int a = 0; a < NA; a++) part[r][a] = fmaf(hv, w[a], part[r][a]);
      }
    }
  }

#pragma unroll
  for (int st = 1; st <= 8; st <<= 1) {
#pragma unroll
    for (int r = 0; r < 4; r++)
#pragma unroll
      for (int a = 0; a < NA; a++)
        part[r][a] += __shfl_xor(part[r][a], st);
  }

  float score0, score1;
  {
    const int r0_ = c16 / 5, a0_ = c16 - 5 * (c16 / 5);
    float lg = 0.0f;
#pragma unroll
    for (int r = 0; r < 4; r++)
#pragma unroll
      for (int a = 0; a < NA; a++)
        if (r0_ == r && a0_ == a) lg = part[r][a];
    const float logit = lg + sbp2[a0_];
    const int growr = base + wave * 16 + h2 * 4 + r0_;
    score0 = gumbel_at((uint32_t)(growr * NA + a0_)) + logit;
  }
  {
    const int a1_ = (c16 & 3) + 1;
    float lg = 0.0f;
#pragma unroll
    for (int a = 1; a < NA; a++)
      if (a1_ == a) lg = part[3][a];
    const float logit = lg + sbp2[a1_];
    const int growr = base + wave * 16 + h2 * 4 + 3;
    score1 = gumbel_at((uint32_t)(growr * NA + a1_)) + logit;
  }

  int best = 0;
  float bs = 0.0f;
#pragma unroll
  for (int a = 0; a < NA; a++) {
    const int idx = c16 * 5 + a;
    const int src = h2 * 16 + ((idx < 16) ? idx : (idx - 16));
    const float v0 = __shfl(score0, src);
    const float v1 = __shfl(score1, src);
    const float s = (idx < 16) ? v0 : v1;
    if (a == 0) bs = s;
    else if (s > bs) { bs = s; best = a; }
  }
  // ---- local bucketing (r5/r6-proven pattern) ----
  if (c16 < 4) {
    const int rl = wave * 16 + h2 * 4 + c16;
    const int p = atomicAdd(&sBCnt[best], 1);
    sBList[best][p] = (ushort)rl;
  }
  __syncthreads();
  // ---- reserve global segments + copy lists ----
  if (tid < NA) sBase[tid] = atomicAdd(&gcnt[tid], sBCnt[tid]);
  __syncthreads();
#pragma unroll
  for (int a = 0; a < NA; a++) {
    const int c = sBCnt[a], gb = sBase[a];
    for (int i = tid; i < c; i += 512)
      glist[a * B_N + gb + i] = base + (int)sBList[a][i];
  }

  // ---- wemb gather (independent output half) ----
#pragma unroll 1
  for (int i = tid; i < 128 * 16; i += 512) {
    const int row = i >> 4, seg = i & 15;
    ((float4*)out_wemb)[(size_t)(base + row) * 16 + seg] =
        ((const float4*)wemb)[(size_t)y[base + row] * 16 + seg];
  }
}

// ---------- Phase 2: expert (r14 core; rows from prebuilt global lists) -----
__global__ __launch_bounds__(512, 1) void expert_staged(
    const int* __restrict__ x, const float* __restrict__ cemb,
    const float* __restrict__ be1, const float* __restrict__ be2,
    const int* __restrict__ gcnt, const int* __restrict__ glist,
    const ushort* __restrict__ wPrep, float* __restrict__ out) {
  __shared__ __align__(16) ushort sW1[16384];    // 32 KB
  __shared__ __align__(16) ushort sW2[8192];     // 16 KB
  __shared__ __align__(16) ushort sHt[8][2048];  // 32 KB (4 KB / wave)
  __shared__ __align__(16) float sbe1[NH];
  __shared__ __align__(16) float sbe2[NIW];
  __shared__ int sList[P2_R];

  const int tid = threadIdx.x;
  const int a = blockIdx.x % NA;
  const int chunk = blockIdx.x / NA;

  const int cnt_a = gcnt[a];
  const int len = (cnt_a + P2_NCHUNK - 1) / P2_NCHUNK;
  const int beg = chunk * len;
  int scnt = cnt_a - beg;
  if (scnt > len) scnt = len;
  if (scnt < 0) scnt = 0;

  // ---- weight staging: coalesced short8 copies from prepack (r12 layout) ---
  {
    const short8* s1 = (const short8*)(wPrep + (size_t)a * 24576);
    const short8* s2 = s1 + 2048;
    short8* d1 = (short8*)sW1;
    short8* d2 = (short8*)sW2;
#pragma unroll
    for (int i = 0; i < 4; i++) d1[tid + i * 512] = s1[tid + i * 512];
#pragma unroll
    for (int i = 0; i < 2; i++) d2[tid + i * 512] = s2[tid + i * 512];
    if (tid < NH) sbe1[tid] = be1[a * NH + tid];
    if (tid < NIW) sbe2[tid] = be2[a * NIW + tid];
  }
  // ---- slice copy (replaces compaction scan) ----
  {
    const int* gsrc = glist + a * B_N + beg;
    for (int i = tid; i < scnt; i += 512) sList[i] = gsrc[i];
  }
  __syncthreads();

  if (scnt == 0) return;

  const int wave = tid >> 6, lane = tid & 63;
  const int c16 = lane & 15, h2 = lane >> 4;
  const int rowb = h2 * 4;
  ushort* myHt = sHt[wave];

  int t16 = wave * 16;
  if (t16 >= scnt) return;

  // preload first tile's raw A data
  float4 raw[8];
  {
    const int slot = t16 + c16;
    const int g = sList[(slot < scnt) ? slot : 0];
    const int2 xi2 = ((const int2*)x)[g];
#pragma unroll
    for (int kt = 0; kt < 4; kt++) {
      const float* src = cemb + (size_t)((kt < 2) ? xi2.x : xi2.y) * NIC +
                         (kt & 1) * 32 + h2 * 8;
      raw[2 * kt]     = *(const float4*)src;
      raw[2 * kt + 1] = *(const float4*)(src + 4);
    }
  }

#pragma unroll 1
  while (t16 < scnt) {
    const int tn = t16 + 128;

    short8 Ae[4];
#pragma unroll
    for (int kt = 0; kt < 4; kt++) {
      const float4 aa = raw[2 * kt], bb = raw[2 * kt + 1];
      short8 pk;
      pk[0] = (short)f2bf(aa.x); pk[1] = (short)f2bf(aa.y);
      pk[2] = (short)f2bf(aa.z); pk[3] = (short)f2bf(aa.w);
      pk[4] = (short)f2bf(bb.x); pk[5] = (short)f2bf(bb.y);
      pk[6] = (short)f2bf(bb.z); pk[7] = (short)f2bf(bb.w);
      Ae[kt] = pk;
    }

    if (tn < scnt) {
      const int slot = tn + c16;
      const int g = sList[(slot < scnt) ? slot : 0];
      const int2 xi2 = ((const int2*)x)[g];
#pragma unroll
      for (int kt = 0; kt < 4; kt++) {
        const float* src = cemb + (size_t)((kt < 2) ? xi2.x : xi2.y) * NIC +
                           (kt & 1) * 32 + h2 * 8;
        raw[2 * kt]     = *(const float4*)src;
        raw[2 * kt + 1] = *(const float4*)(src + 4);
      }
    }

    // L1: relu(C @ We1 + be1) -> myHt (A-frag layout), verbatim core
#pragma unroll
    for (int ct = 0; ct < 8; ct++) {
      const int n = ct * 16 + c16;
      const float bv = sbe1[n];
      f32x4 acc = {bv, bv, bv, bv};
#pragma unroll
      for (int kt = 0; kt < 4; kt++) {
        const short8 Bf = *(const short8*)&sW1[(ct * 4 + kt) * 512 + lane * 8];
        acc = __builtin_amdgcn_mfma_f32_16x16x32_bf16(Ae[kt], Bf, acc, 0, 0, 0);
      }
      const int kt2 = n >> 5, grp2 = (n & 31) >> 3, j2 = n & 7;
#pragma unroll
      for (int r = 0; r < 4; r++)
        myHt[kt2 * 512 + ((rowb + r) + 16 * grp2) * 8 + j2] =
            f2bf(fmaxf(acc[r], 0.0f));
    }

    // L2: h @ We2 + be2 -> masked scatter (verbatim core)
    short8 A2[4];
#pragma unroll
    for (int kt = 0; kt < 4; kt++)
      A2[kt] = *(const short8*)&myHt[kt * 512 + lane * 8];
    int gr4[4];
#pragma unroll
    for (int r = 0; r < 4; r++) {
      const int li2 = t16 + rowb + r;
      gr4[r] = (li2 < scnt) ? sList[li2] : -1;
    }
#pragma unroll
    for (int ot = 0; ot < 4; ot++) {
      const int o = ot * 16 + c16;
      const float bv = sbe2[o];
      f32x4 o4 = {bv, bv, bv, bv};
#pragma unroll
      for (int kt = 0; kt < 4; kt++) {
        const short8 Bf = *(const short8*)&sW2[(ot * 4 + kt) * 512 + lane * 8];
        o4 = __builtin_amdgcn_mfma_f32_16x16x32_bf16(A2[kt], Bf, o4, 0, 0, 0);
      }
#pragma unroll
      for (int r = 0; r < 4; r++)
        if (gr4[r] >= 0) out[(size_t)gr4[r] * NIW + o] = o4[r];
    }

    t16 = tn;
  }
}

extern "C" void kernel_launch(void* const* d_in, const int* in_sizes, int n_in,
                              void* d_out, int out_size, void* d_ws, size_t ws_size,
                              hipStream_t stream) {
  const int*   x    = (const int*)d_in[0];
  const int*   y    = (const int*)d_in[1];
  const float* cemb = (const float*)d_in[2];
  const float* wemb = (const float*)d_in[3];
  const float* Wp1  = (const float*)d_in[4];
  const float* bp1  = (const float*)d_in[5];
  const float* Wp2  = (const float*)d_in[6];
  const float* bp2  = (const float*)d_in[7];
  const float* We1  = (const float*)d_in[8];
  const float* be1  = (const float*)d_in[9];
  const float* We2  = (const float*)d_in[10];
  const float* be2  = (const float*)d_in[11];

  float* out      = (float*)d_out;
  float* out_wemb = out + (size_t)B_N * NIW;
  int*    gcnt  = (int*)d_ws;
  int*    glist = (int*)((char*)d_ws + WS_GLIST_OFF);
  ushort* wPrep = (ushort*)((char*)d_ws + WS_PREP_OFF);

  hipMemsetAsync(d_ws, 0, WS_GLIST_OFF, stream);   // zero gcnt each call
  policy_kernel<<<NBLK + NA, 512, 0, stream>>>(
      x, y, cemb, wemb, Wp1, bp1, Wp2, bp2, We1, We2,
      out_wemb, gcnt, glist, wPrep);
  expert_staged<<<NA * P2_NCHUNK, 512, 0, stream>>>(
      x, cemb, be1, be2, gcnt, glist, wPrep, out);
}

// Round 16
// 41.547 us; speedup vs baseline: 1.1757x; 1.1757x over previous
//
#include <hip/hip_runtime.h>
#include <stdint.h>

#define B_N   65536
#define NIC   64
#define NIW   64
#define NH    128
#define NA    5
#define D2    128   // 2*NIC

#define PARTITIONABLE 1

#define P2_NCHUNK 51
#define P2_R      1286  // ceil(B_N / P2_NCHUNK)

typedef __attribute__((ext_vector_type(8))) short short8;
typedef __attribute__((ext_vector_type(4))) float f32x4;

__device__ __forceinline__ ushort f2bf(float f) {
  uint32_t u = __float_as_uint(f);
  uint32_t r = (u + 0x7FFFu + ((u >> 16) & 1u)) >> 16;  // RNE
  return (ushort)r;
}

__device__ __forceinline__ void split2(float f, ushort& h, ushort& l) {
  h = f2bf(f);
  l = f2bf(f - __uint_as_float(((uint32_t)h) << 16));
}

__device__ __forceinline__ void threefry2x32_k042(uint32_t x0, uint32_t x1,
                                                  uint32_t& o0, uint32_t& o1) {
  const uint32_t ks0 = 0u;
  const uint32_t ks1 = 42u;
  const uint32_t ks2 = 0x1BD11BDAu ^ 0u ^ 42u;
  x0 += ks0; x1 += ks1;
#define TF_RND(r) { x0 += x1; x1 = (x1 << (r)) | (x1 >> (32 - (r))); x1 ^= x0; }
  TF_RND(13) TF_RND(15) TF_RND(26) TF_RND(6)
  x0 += ks1; x1 += ks2 + 1u;
  TF_RND(17) TF_RND(29) TF_RND(16) TF_RND(24)
  x0 += ks2; x1 += ks0 + 2u;
  TF_RND(13) TF_RND(15) TF_RND(26) TF_RND(6)
  x0 += ks0; x1 += ks1 + 3u;
  TF_RND(17) TF_RND(29) TF_RND(16) TF_RND(24)
  x0 += ks1; x1 += ks2 + 4u;
  TF_RND(13) TF_RND(15) TF_RND(26) TF_RND(6)
  x0 += ks2; x1 += ks0 + 5u;
#undef TF_RND
  o0 = x0; o1 = x1;
}

__device__ __forceinline__ float gumbel_at(uint32_t idx) {
  uint32_t bits;
#if PARTITIONABLE
  uint32_t a, b;
  threefry2x32_k042(0u, idx, a, b);
  bits = a ^ b;
#else
  const uint32_t HALF = (uint32_t)(B_N * NA) / 2u;
  uint32_t a, b;
  if (idx < HALF) { threefry2x32_k042(idx, idx + HALF, a, b); bits = a; }
  else            { threefry2x32_k042(idx - HALF, idx, a, b); bits = b; }
#endif
  const float f = __uint_as_float((bits >> 9) | 0x3f800000u) - 1.0f;
  const double u = (f == 0.0f) ? (double)0x1p-126 : (double)f;
  const float nl = (float)(-log(u));
  const float g  = (float)(-log((double)nl));
  return g;
}

// ---------------- Phase 1: policy MLP, in-register epilogue (r8 verbatim) ---
// A-frag: row = lane&15, k = 32*kt + 8*(lane>>4) + j
// D     : col = ct*16 + (lane&15), row(local16) = (lane>>4)*4 + r
__global__ __launch_bounds__(512, 4) void policy_kernel(
    const int* __restrict__ x, const int* __restrict__ y,
    const float* __restrict__ cemb, const float* __restrict__ wemb,
    const float* __restrict__ Wp1, const float* __restrict__ bp1,
    const float* __restrict__ Wp2, const float* __restrict__ bp2,
    float* __restrict__ out_wemb, int* __restrict__ action) {
  __shared__ __align__(16) ushort sW1h[16384];   // 32 KB Wp1 hi frags
  __shared__ __align__(16) ushort sW1l[16384];   // 32 KB Wp1 lo frags
  __shared__ __align__(16) float sW2t[NA][NH];   // Wp2^T
  __shared__ __align__(16) float sb1[NH];
  __shared__ __align__(16) float sbp2[8];

  const int tid = threadIdx.x;
  const int base = blockIdx.x * 128;

  {
    const int n = tid & 127, q = tid >> 7;
    const int fb = (n >> 4) * 4 + q;
    const int cc = n & 15;
#pragma unroll
    for (int grp = 0; grp < 4; grp++) {
      short8 ph, pl;
#pragma unroll
      for (int j = 0; j < 8; j++) {
        const int k = 32 * q + 8 * grp + j;
        ushort hh, ll;
        split2(Wp1[k * NH + n], hh, ll);
        ph[j] = (short)hh;
        pl[j] = (short)ll;
      }
      *(short8*)&sW1h[fb * 512 + (cc + 16 * grp) * 8] = ph;
      *(short8*)&sW1l[fb * 512 + (cc + 16 * grp) * 8] = pl;
    }
    if (tid < NH) sb1[tid] = bp1[tid];
    if (tid < NA * 32) {
      const int a = tid >> 5, k0 = (tid & 31) * 4;
#pragma unroll
      for (int j = 0; j < 4; j++) sW2t[a][k0 + j] = Wp2[(k0 + j) * NA + a];
    }
    if (tid < NA) sbp2[tid] = bp2[tid];
  }

  const int wave = tid >> 6, lane = tid & 63;
  const int c16 = lane & 15, h2 = lane >> 4;

  const int grow = base + wave * 16 + c16;
  const int xi0 = x[grow * 2], xi1 = x[grow * 2 + 1];
  short8 Ah[4], Al[4];
#pragma unroll
  for (int kt = 0; kt < 4; kt++) {
    const int xi = (kt < 2) ? xi0 : xi1;
    const float* src = cemb + (size_t)xi * NIC + (kt & 1) * 32 + h2 * 8;
    const float4 aa = *(const float4*)src;
    const float4 bb = *(const float4*)(src + 4);
    ushort hh, ll;
    short8 ph, pl;
    split2(aa.x, hh, ll); ph[0] = (short)hh; pl[0] = (short)ll;
    split2(aa.y, hh, ll); ph[1] = (short)hh; pl[1] = (short)ll;
    split2(aa.z, hh, ll); ph[2] = (short)hh; pl[2] = (short)ll;
    split2(aa.w, hh, ll); ph[3] = (short)hh; pl[3] = (short)ll;
    split2(bb.x, hh, ll); ph[4] = (short)hh; pl[4] = (short)ll;
    split2(bb.y, hh, ll); ph[5] = (short)hh; pl[5] = (short)ll;
    split2(bb.z, hh, ll); ph[6] = (short)hh; pl[6] = (short)ll;
    split2(bb.w, hh, ll); ph[7] = (short)hh; pl[7] = (short)ll;
    Ah[kt] = ph;
    Al[kt] = pl;
  }
  __syncthreads();   // the only barrier

  float part[4][5];
#pragma unroll
  for (int r = 0; r < 4; r++)
#pragma unroll
    for (int a = 0; a < NA; a++) part[r][a] = 0.0f;

#pragma unroll
  for (int half = 0; half < 2; half++) {
    f32x4 acc[4];
#pragma unroll
    for (int c2 = 0; c2 < 4; c2++) {
      const float bv = sb1[(half * 4 + c2) * 16 + c16];
      acc[c2] = (f32x4){bv, bv, bv, bv};
    }
#pragma unroll
    for (int kt = 0; kt < 4; kt++) {
#pragma unroll
      for (int c2 = 0; c2 < 4; c2++) {
        const int fb = (half * 4 + c2) * 4 + kt;
        const short8 Bh = *(const short8*)&sW1h[fb * 512 + lane * 8];
        const short8 Bl = *(const short8*)&sW1l[fb * 512 + lane * 8];
        acc[c2] = __builtin_amdgcn_mfma_f32_16x16x32_bf16(Ah[kt], Bh, acc[c2], 0, 0, 0);
        acc[c2] = __builtin_amdgcn_mfma_f32_16x16x32_bf16(Al[kt], Bh, acc[c2], 0, 0, 0);
        acc[c2] = __builtin_amdgcn_mfma_f32_16x16x32_bf16(Ah[kt], Bl, acc[c2], 0, 0, 0);
      }
    }
#pragma unroll
    for (int c2 = 0; c2 < 4; c2++) {
      const int ct = half * 4 + c2;
      float w[NA];
#pragma unroll
      for (int a = 0; a < NA; a++) w[a] = sW2t[a][ct * 16 + c16];
#pragma unroll
      for (int r = 0; r < 4; r++) {
        const float hv = fmaxf(acc[c2][r], 0.0f);
#pragma unroll
        for (int a = 0; a < NA; a++) part[r][a] = fmaf(hv, w[a], part[r][a]);
      }
    }
  }

#pragma unroll
  for (int st = 1; st <= 8; st <<= 1) {
#pragma unroll
    for (int r = 0; r < 4; r++)
#pragma unroll
      for (int a = 0; a < NA; a++)
        part[r][a] += __shfl_xor(part[r][a], st);
  }

  float score0, score1;
  {
    const int r0_ = c16 / 5, a0_ = c16 - 5 * (c16 / 5);
    float lg = 0.0f;
#pragma unroll
    for (int r = 0; r < 4; r++)
#pragma unroll
      for (int a = 0; a < NA; a++)
        if (r0_ == r && a0_ == a) lg = part[r][a];
    const float logit = lg + sbp2[a0_];
    const int growr = base + wave * 16 + h2 * 4 + r0_;
    score0 = gumbel_at((uint32_t)(growr * NA + a0_)) + logit;
  }
  {
    const int a1_ = (c16 & 3) + 1;
    float lg = 0.0f;
#pragma unroll
    for (int a = 1; a < NA; a++)
      if (a1_ == a) lg = part[3][a];
    const float logit = lg + sbp2[a1_];
    const int growr = base + wave * 16 + h2 * 4 + 3;
    score1 = gumbel_at((uint32_t)(growr * NA + a1_)) + logit;
  }

  int best = 0;
  float bs = 0.0f;
#pragma unroll
  for (int a = 0; a < NA; a++) {
    const int idx = c16 * 5 + a;
    const int src = h2 * 16 + ((idx < 16) ? idx : (idx - 16));
    const float v0 = __shfl(score0, src);
    const float v1 = __shfl(score1, src);
    const float s = (idx < 16) ? v0 : v1;
    if (a == 0) bs = s;
    else if (s > bs) { bs = s; best = a; }
  }
  if (c16 < 4) action[base + wave * 16 + h2 * 4 + c16] = best;

#pragma unroll 1
  for (int i = tid; i < 128 * 16; i += 512) {
    const int row = i >> 4, seg = i & 15;
    ((float4*)out_wemb)[(size_t)(base + row) * 16 + seg] =
        ((const float4*)wemb)[(size_t)y[base + row] * 16 + seg];
  }
}

// ---------- Phase 2: self-staging expert (r8 + ballot compaction + reg A) ---
__global__ __launch_bounds__(512, 1) void expert_staged(
    const int* __restrict__ x, const float* __restrict__ cemb,
    const float* __restrict__ We1, const float* __restrict__ be1,
    const float* __restrict__ We2, const float* __restrict__ be2,
    const int* __restrict__ action, float* __restrict__ out) {
  __shared__ __align__(16) ushort sW1[16384];    // 32 KB
  __shared__ __align__(16) ushort sW2[8192];     // 16 KB
  __shared__ __align__(16) ushort sHt[8][2048];  // 32 KB (4 KB / wave)
  __shared__ __align__(16) float sbe1[NH];
  __shared__ __align__(16) float sbe2[NIW];
  __shared__ int sList[P2_R];
  __shared__ int sCount;

  const int tid = threadIdx.x;
  const int a = blockIdx.x % NA;
  const int chunk = blockIdx.x / NA;
  const int rowBeg = chunk * P2_R;
  const int rowEnd = (rowBeg + P2_R < B_N) ? rowBeg + P2_R : B_N;

  const int wave = tid >> 6, lane = tid & 63;

  if (tid == 0) sCount = 0;
  __syncthreads();

  // ---- ballot compaction: one atomic per wave per stripe ----
  for (int r0 = rowBeg; r0 < rowEnd; r0 += 512) {
    const int r = r0 + tid;
    const bool m = (r < rowEnd) && (action[r] == a);
    const unsigned long long mask = __ballot(m);
    const int wcnt = __popcll(mask);
    int wbase = 0;
    if (lane == 0 && wcnt) wbase = atomicAdd(&sCount, wcnt);
    wbase = __shfl(wbase, 0);
    if (m)
      sList[wbase + __popcll(mask & ((1ull << lane) - 1ull))] = r;
  }

  // ---- weight staging (r8 verbatim conversion) ----
  {
    const float* W1g = We1 + (size_t)a * D2 * NH;
    const int n = tid & 127, q = tid >> 7;
    const int fb = (n >> 4) * 4 + q;
    const int cc = n & 15;
#pragma unroll
    for (int grp = 0; grp < 4; grp++) {
      short8 pk;
#pragma unroll
      for (int j = 0; j < 8; j++)
        pk[j] = (short)f2bf(W1g[(32 * q + 8 * grp + j) * NH + n]);
      *(short8*)&sW1[fb * 512 + (cc + 16 * grp) * 8] = pk;
    }
    if (tid < NH) sbe1[tid] = be1[a * NH + tid];
    if (tid < NIW) sbe2[tid] = be2[a * NIW + tid];
  }
  {
    const float* W2g = We2 + (size_t)a * NH * NIW;
    const int o = tid & 63, hq = tid >> 6;
    const int fb = (o >> 4) * 4 + (hq >> 1);
    const int cc = o & 15;
#pragma unroll
    for (int g2 = 0; g2 < 2; g2++) {
      const int grp = (hq & 1) * 2 + g2;
      short8 pk;
#pragma unroll
      for (int j = 0; j < 8; j++)
        pk[j] = (short)f2bf(W2g[(16 * hq + 8 * g2 + j) * NIW + o]);
      *(short8*)&sW2[fb * 512 + (cc + 16 * grp) * 8] = pk;
    }
  }
  __syncthreads();

  const int cnt = sCount;
  if (cnt == 0) return;

  const int c16 = lane & 15, h2 = lane >> 4;
  const int rowb = h2 * 4;
  ushort* myHt = sHt[wave];

#pragma unroll 1
  for (int t16 = wave * 16; t16 < cnt; t16 += 128) {
    // A-frags in registers (r10/r11-proven mapping; no sCt round-trip)
    const int slot = t16 + c16;
    const int g = sList[(slot < cnt) ? slot : 0];
    const int2 xi2 = ((const int2*)x)[g];
    short8 Ae[4];
#pragma unroll
    for (int kt = 0; kt < 4; kt++) {
      const float* src = cemb + (size_t)((kt < 2) ? xi2.x : xi2.y) * NIC +
                         (kt & 1) * 32 + h2 * 8;
      const float4 aa = *(const float4*)src;
      const float4 bb = *(const float4*)(src + 4);
      short8 pk;
      pk[0] = (short)f2bf(aa.x); pk[1] = (short)f2bf(aa.y);
      pk[2] = (short)f2bf(aa.z); pk[3] = (short)f2bf(aa.w);
      pk[4] = (short)f2bf(bb.x); pk[5] = (short)f2bf(bb.y);
      pk[6] = (short)f2bf(bb.z); pk[7] = (short)f2bf(bb.w);
      Ae[kt] = pk;
    }

    // L1: relu(C @ We1 + be1) -> myHt (A-frag layout), r8 verbatim core
#pragma unroll
    for (int ct = 0; ct < 8; ct++) {
      const int n = ct * 16 + c16;
      const float bv = sbe1[n];
      f32x4 acc = {bv, bv, bv, bv};
#pragma unroll
      for (int kt = 0; kt < 4; kt++) {
        const short8 Bf = *(const short8*)&sW1[(ct * 4 + kt) * 512 + lane * 8];
        acc = __builtin_amdgcn_mfma_f32_16x16x32_bf16(Ae[kt], Bf, acc, 0, 0, 0);
      }
      const int kt2 = n >> 5, grp2 = (n & 31) >> 3, j2 = n & 7;
#pragma unroll
      for (int r = 0; r < 4; r++)
        myHt[kt2 * 512 + ((rowb + r) + 16 * grp2) * 8 + j2] =
            f2bf(fmaxf(acc[r], 0.0f));
    }

    // L2: h @ We2 + be2 -> masked scatter (r8 verbatim core)
    short8 A2[4];
#pragma unroll
    for (int kt = 0; kt < 4; kt++)
      A2[kt] = *(const short8*)&myHt[kt * 512 + lane * 8];
    int gr4[4];
#pragma unroll
    for (int r = 0; r < 4; r++) {
      const int li2 = t16 + rowb + r;
      gr4[r] = (li2 < cnt) ? sList[li2] : -1;
    }
#pragma unroll
    for (int ot = 0; ot < 4; ot++) {
      const int o = ot * 16 + c16;
      const float bv = sbe2[o];
      f32x4 o4 = {bv, bv, bv, bv};
#pragma unroll
      for (int kt = 0; kt < 4; kt++) {
        const short8 Bf = *(const short8*)&sW2[(ot * 4 + kt) * 512 + lane * 8];
        o4 = __builtin_amdgcn_mfma_f32_16x16x32_bf16(A2[kt], Bf, o4, 0, 0, 0);
      }
#pragma unroll
      for (int r = 0; r < 4; r++)
        if (gr4[r] >= 0) out[(size_t)gr4[r] * NIW + o] = o4[r];
    }
  }
}

extern "C" void kernel_launch(void* const* d_in, const int* in_sizes, int n_in,
                              void* d_out, int out_size, void* d_ws, size_t ws_size,
                              hipStream_t stream) {
  const int*   x    = (const int*)d_in[0];
  const int*   y    = (const int*)d_in[1];
  const float* cemb = (const float*)d_in[2];
  const float* wemb = (const float*)d_in[3];
  const float* Wp1  = (const float*)d_in[4];
  const float* bp1  = (const float*)d_in[5];
  const float* Wp2  = (const float*)d_in[6];
  const float* bp2  = (const float*)d_in[7];
  const float* We1  = (const float*)d_in[8];
  const float* be1  = (const float*)d_in[9];
  const float* We2  = (const float*)d_in[10];
  const float* be2  = (const float*)d_in[11];

  float* out      = (float*)d_out;
  float* out_wemb = out + (size_t)B_N * NIW;
  int*   action   = (int*)d_ws;   // 256 KB (proven)

  policy_kernel<<<B_N / 128, 512, 0, stream>>>(
      x, y, cemb, wemb, Wp1, bp1, Wp2, bp2, out_wemb, action);
  expert_staged<<<NA * P2_NCHUNK, 512, 0, stream>>>(
      x, cemb, We1, be1, We2, be2, action, out);
}